// Round 1
// baseline (551.902 us; speedup 1.0000x reference)
//
#include <hip/hip_runtime.h>

#define NN 65536
#define NE 1048576
#define HID 80

// ---------------- input projection: h = x @ W_in + b_in ----------------
__global__ __launch_bounds__(256) void k_in(const float* __restrict__ x,
    const float* __restrict__ W, const float* __restrict__ b,
    float* __restrict__ h) {
  int idx = blockIdx.x * 256 + threadIdx.x;
  if (idx >= NN * HID) return;
  int n = idx / HID, c = idx % HID;
  const float* xr = x + n * 16;
  float acc = b[c];
#pragma unroll
  for (int i = 0; i < 16; i++) acc += xr[i] * W[i * HID + c];
  h[idx] = acc;
}

// ---------------- CSR build ----------------
__global__ __launch_bounds__(256) void k_hist(const int* __restrict__ dst,
                                              int* __restrict__ counts) {
  int idx = blockIdx.x * 256 + threadIdx.x;
  if (idx < NE) atomicAdd(&counts[dst[idx]], 1);
}

__global__ __launch_bounds__(1024) void k_scan(const int* __restrict__ counts,
    int* __restrict__ offsets, int* __restrict__ cursors) {
  __shared__ int part[1024];
  int t = threadIdx.x;
  int base = t * 64;
  int s = 0;
  for (int j = 0; j < 64; j++) s += counts[base + j];
  part[t] = s;
  __syncthreads();
  for (int offd = 1; offd < 1024; offd <<= 1) {
    int v = (t >= offd) ? part[t - offd] : 0;
    __syncthreads();
    part[t] += v;
    __syncthreads();
  }
  int run = (t == 0) ? 0 : part[t - 1];
  for (int j = 0; j < 64; j++) {
    offsets[base + j] = run;
    cursors[base + j] = run;
    run += counts[base + j];
  }
}

__global__ __launch_bounds__(256) void k_fill(const int* __restrict__ src,
    const int* __restrict__ dst, const float4* __restrict__ eattr,
    int* __restrict__ cursors, int* __restrict__ src_sorted,
    float4* __restrict__ eattr_sorted) {
  int idx = blockIdx.x * 256 + threadIdx.x;
  if (idx >= NE) return;
  int d = dst[idx];
  int pos = atomicAdd(&cursors[d], 1);
  src_sorted[pos] = src[idx];
  eattr_sorted[pos] = eattr[idx];
}

// ---------------- per-layer message + aggregate + post-matmul ----------------
// Quarter-wave (16 lanes) per dst node. Lane owns components c = lane + 16*i.
// Phase A: R_j[c] = sum_{e->n} coef_j[e] * h_in[src_e][c]   (registers)
// Phase B: R -> LDS
// Phase C: h_out[n] = weights applied to R (all norm constants folded, incl 1/sqrt(DEG))
__global__ __launch_bounds__(256) void k_msg(const float* __restrict__ h_in,
    float* __restrict__ h_out,
    const float* __restrict__ w1, const float* __restrict__ w2,
    const float* __restrict__ w3, const float* __restrict__ w4,
    const int* __restrict__ offsets, const int* __restrict__ counts,
    const int* __restrict__ src_sorted,
    const float4* __restrict__ eattr_sorted) {
  __shared__ float Rlds[16][4][81];  // +1 pad: quarters land in different banks
  __shared__ float w1s[1024], w2s[512], w3s[512], w4s[256];
  int tid = threadIdx.x;
  for (int i = tid; i < 1024; i += 256) w1s[i] = w1[i];
  for (int i = tid; i < 512; i += 256) w2s[i] = w2[i];
  for (int i = tid; i < 512; i += 256) w3s[i] = w3[i];
  if (tid < 256) w4s[tid] = w4[tid];

  int q = tid >> 4;
  int lane = tid & 15;
  int n = (blockIdx.x << 4) + q;

  float R[4][5];
#pragma unroll
  for (int j = 0; j < 4; j++)
#pragma unroll
    for (int i = 0; i < 5; i++) R[j][i] = 0.f;

  int start = offsets[n];
  int deg = counts[n];
  for (int e = 0; e < deg; e++) {
    int rec = start + e;
    int s = src_sorted[rec];
    float4 cf = eattr_sorted[rec];
    const float* hp = h_in + s * HID + lane;
    float hv[5];
    hv[0] = hp[0];
    hv[1] = hp[16];
    hv[2] = hp[32];
    hv[3] = hp[48];
    hv[4] = hp[64];
#pragma unroll
    for (int i = 0; i < 5; i++) {
      R[0][i] += cf.x * hv[i];
      R[1][i] += cf.y * hv[i];
      R[2][i] += cf.z * hv[i];
      R[3][i] += cf.w * hv[i];
    }
  }

#pragma unroll
  for (int j = 0; j < 4; j++)
#pragma unroll
    for (int i = 0; i < 5; i++) Rlds[q][j][lane + 16 * i] = R[j][i];
  __syncthreads();

  // norm constants: c=1/sqrt(2); per-path fan-in norm; and 1/sqrt(DEG)=1/4 folded in
  const float C1 = 0.03125f;       // 1/(sqrt2*sqrt32*4)
  const float C2 = 0.025515518f;   // 1/(sqrt2*sqrt48*4)
  const float C3 = 0.03125f;       // 1/(sqrt2*sqrt32*4)
  const float C4 = 0.044194174f;   // 1/(sqrt2*sqrt16*4)

  float outv[5];
#pragma unroll
  for (int i = 0; i < 5; i++) {
    int c = lane + 16 * i;
    float acc;
    if (c < 32) {  // scalar outputs (i=0,1) -- uniform across wave
      float a1 = 0.f, a2 = 0.f;
#pragma unroll
      for (int a = 0; a < 32; a++) a1 += Rlds[q][0][a] * w1s[a * 32 + c];
#pragma unroll
      for (int a = 0; a < 16; a++) {
        float T = Rlds[q][1][32 + 3 * a] + Rlds[q][2][33 + 3 * a] +
                  Rlds[q][3][34 + 3 * a];
        a2 += T * w2s[a * 32 + c];
      }
      acc = C1 * a1 + C2 * a2;
    } else {  // vector outputs (i=2,3,4)
      int cv = (c - 32) / 3, k = (c - 32) % 3;
      float a3 = 0.f, a4 = 0.f;
#pragma unroll
      for (int a = 0; a < 32; a++) a3 += Rlds[q][k + 1][a] * w3s[a * 16 + cv];
#pragma unroll
      for (int a = 0; a < 16; a++)
        a4 += Rlds[q][0][32 + 3 * a + k] * w4s[a * 16 + cv];
      acc = C3 * a3 + C4 * a4;
    }
    outv[i] = acc;
  }
  float* op = h_out + n * HID + lane;
  op[0] = outv[0];
  op[16] = outv[1];
  op[32] = outv[2];
  op[48] = outv[3];
  op[64] = outv[4];
}

// ---------------- output projection: out = relu(h) @ W_out + b_out ----------------
__global__ __launch_bounds__(256) void k_out(const float* __restrict__ h,
    const float* __restrict__ W, const float* __restrict__ b,
    float* __restrict__ out) {
  int idx = blockIdx.x * 256 + threadIdx.x;
  if (idx >= NN * 8) return;
  int n = idx >> 3, c = idx & 7;
  const float* hr = h + n * HID;
  float acc = b[c];
#pragma unroll 8
  for (int a = 0; a < HID; a++) {
    float v = hr[a];
    v = v > 0.f ? v : 0.f;
    acc += v * W[a * 8 + c];
  }
  out[idx] = acc;
}

extern "C" void kernel_launch(void* const* d_in, const int* in_sizes, int n_in,
                              void* d_out, int out_size, void* d_ws,
                              size_t ws_size, hipStream_t stream) {
  const float* x = (const float*)d_in[0];
  const int* ei = (const int*)d_in[1];
  const float* eattr = (const float*)d_in[2];
  const float* W_in = (const float*)d_in[3];
  const float* b_in = (const float*)d_in[4];
  const float* tp_w1 = (const float*)d_in[5];
  const float* tp_w2 = (const float*)d_in[6];
  const float* tp_w3 = (const float*)d_in[7];
  const float* tp_w4 = (const float*)d_in[8];
  const float* W_out = (const float*)d_in[9];
  const float* b_out = (const float*)d_in[10];
  float* out = (float*)d_out;

  char* ws = (char*)d_ws;
  size_t off = 0;
  auto alloc = [&](size_t bytes) {
    void* p = ws + off;
    off += (bytes + 255) & ~size_t(255);
    return p;
  };
  float* h_a = (float*)alloc((size_t)NN * HID * 4);
  float* h_b = (float*)alloc((size_t)NN * HID * 4);
  int* counts = (int*)alloc((size_t)NN * 4);
  int* offsets = (int*)alloc((size_t)NN * 4);
  int* cursors = (int*)alloc((size_t)NN * 4);
  int* src_sorted = (int*)alloc((size_t)NE * 4);
  float4* eattr_sorted = (float4*)alloc((size_t)NE * 16);

  const int* src = ei;
  const int* dst = ei + NE;

  hipMemsetAsync(counts, 0, (size_t)NN * 4, stream);
  k_in<<<(NN * HID + 255) / 256, 256, 0, stream>>>(x, W_in, b_in, h_a);
  k_hist<<<NE / 256, 256, 0, stream>>>(dst, counts);
  k_scan<<<1, 1024, 0, stream>>>(counts, offsets, cursors);
  k_fill<<<NE / 256, 256, 0, stream>>>(src, dst, (const float4*)eattr, cursors,
                                       src_sorted, eattr_sorted);

  float* hin = h_a;
  float* hout = h_b;
  for (int l = 0; l < 3; l++) {
    k_msg<<<NN / 16, 256, 0, stream>>>(hin, hout, tp_w1 + l * 1024,
                                       tp_w2 + l * 512, tp_w3 + l * 512,
                                       tp_w4 + l * 256, offsets, counts,
                                       src_sorted, eattr_sorted);
    float* t = hin;
    hin = hout;
    hout = t;
  }
  k_out<<<(NN * 8 + 255) / 256, 256, 0, stream>>>(hin, W_out, b_out, out);
}